// Round 1
// baseline (1345.680 us; speedup 1.0000x reference)
//
#include <hip/hip_runtime.h>
#include <stdint.h>

#define NPTS 4096
#define THREADS 1024
#define PER (NPTS / THREADS)

// monotonic float32 -> uint32 mapping (order-preserving), and inverse
__device__ __forceinline__ uint32_t f2s(float f) {
    uint32_t u = __float_as_uint(f);
    return (u & 0x80000000u) ? ~u : (u | 0x80000000u);
}
__device__ __forceinline__ float s2f(uint32_t s) {
    uint32_t u = (s & 0x80000000u) ? (s ^ 0x80000000u) : ~s;
    return __uint_as_float(u);
}

__global__ void __launch_bounds__(THREADS)
nms_all(const float* __restrict__ logits,   // [N,3]
        const float* __restrict__ boxes,    // [N,2]
        const float* __restrict__ tsz,      // [2] (w,h)
        float* __restrict__ out)            // [N,5]
{
    const int cls = blockIdx.x;   // 0 = end_pt, 1 = junction_pt
    const int tid = threadIdx.x;

    __shared__ uint64_t A[NPTS];   // sort keys; reused as float2 pts after sort
    __shared__ float    ssc[NPTS]; // sorted scores
    __shared__ uint8_t  keep[NPTS];
    __shared__ float    kx[64], ky[64];
    __shared__ int      s_nvalid, s_m;

    if (tid == 0) s_nvalid = 0;
    __syncthreads();

    const float w = tsz[0], h = tsz[1];
    const uint32_t VTH = f2s(0.05f);

    // ---- phase 1: softmax, keys, direct outputs (cols 0..2) ----
    int lv = 0;
    for (int r = 0; r < PER; ++r) {
        int i = tid + r * THREADS;
        float x0 = logits[i*3+0], x1 = logits[i*3+1], x2 = logits[i*3+2];
        float mx = fmaxf(x0, fmaxf(x1, x2));
        float e0 = expf(x0 - mx), e1 = expf(x1 - mx), e2 = expf(x2 - mx);
        float sum = e0 + e1 + e2;
        if (cls == 0) {
            out[i*5+0] = 1.0f - e2 / sum;          // tgt score
            out[i*5+1] = boxes[i*2+0] * w;         // x (exact)
            out[i*5+2] = boxes[i*2+1] * h;         // y (exact)
        }
        float sc = (cls == 0 ? e0 : e1) / sum;
        bool valid = sc >= 0.05f;
        uint32_t su = valid ? f2s(sc) : 0u;        // invalid sorts last
        // tie-break: smaller original index first under DESCENDING sort
        A[i] = ((uint64_t)su << 32) | (uint32_t)(~(uint32_t)i);
        lv += valid ? 1 : 0;
    }
    atomicAdd(&s_nvalid, lv);
    __syncthreads();

    // ---- phase 2: bitonic sort, descending (stable via composite key) ----
    for (int k = 2; k <= NPTS; k <<= 1) {
        for (int j = k >> 1; j > 0; j >>= 1) {
            for (int r = 0; r < PER; ++r) {
                int i = tid + r * THREADS;
                int l = i ^ j;
                if (l > i) {
                    uint64_t a = A[i], b = A[l];
                    bool up = ((i & k) == 0);
                    if (up ? (a < b) : (a > b)) { A[i] = b; A[l] = a; }
                }
            }
            __syncthreads();
        }
    }

    // ---- phase 3: unpack keys -> sorted scores/points/valid flags ----
    uint64_t myk[PER];
    for (int r = 0; r < PER; ++r) myk[r] = A[tid + r * THREADS];
    __syncthreads();
    float2* pts = (float2*)A;      // reuse key storage
    for (int r = 0; r < PER; ++r) {
        int s = tid + r * THREADS;
        uint64_t kk = myk[r];
        uint32_t su  = (uint32_t)(kk >> 32);
        uint32_t idx = ~(uint32_t)kk;
        bool valid = su >= VTH;
        ssc[s]  = valid ? s2f(su) : 0.0f;
        float px = boxes[idx*2+0] * w;
        float py = boxes[idx*2+1] * h;
        pts[s] = make_float2(px, py);
        keep[s] = valid ? 1 : 0;
    }
    __syncthreads();

    // ---- phase 4: exact greedy NMS, 64-slot chunks ----
    const int nvalid  = s_nvalid;
    const int nchunks = (nvalid + 63) >> 6;
    const int lane = tid & 63;
    const int wav  = tid >> 6;

    for (int c = 0; c < nchunks; ++c) {
        const int base = c << 6;
        if (wav == 0) {
            // wave 0: sequential intra-chunk resolution, in-register
            int g = base + lane;
            float2 p = pts[g];
            bool alive = keep[g] != 0;
            for (int t = 0; t < 64; ++t) {
                uint64_t bal = __ballot(alive);
                if ((bal >> t) & 1ull) {            // slot t kept -> suppress later
                    float xt = __shfl(p.x, t);
                    float yt = __shfl(p.y, t);
                    if (lane > t && alive) {
                        float dx = __fsub_rn(p.x, xt);
                        float dy = __fsub_rn(p.y, yt);
                        float d2 = __fadd_rn(__fmul_rn(dx, dx), __fmul_rn(dy, dy));
                        if (d2 < 25.0f) alive = false;
                    }
                }
            }
            uint64_t km = __ballot(alive);
            keep[g] = alive ? 1 : 0;
            if (alive) {                            // compact kept-point list
                int pos = __popcll(km & ((1ull << lane) - 1ull));
                kx[pos] = p.x; ky[pos] = p.y;
            }
            if (lane == 0) s_m = __popcll(km);
        }
        __syncthreads();
        const int m = s_m;
        if (m > 0) {
            // all waves: suppress later slots against this chunk's kept points
            for (int r = 0; r < PER; ++r) {
                int jslot = tid + r * THREADS;
                if (jslot >= base + 64 && jslot < nvalid && keep[jslot]) {
                    float2 p = pts[jslot];
                    for (int t = 0; t < m; ++t) {
                        float dx = __fsub_rn(p.x, kx[t]);
                        float dy = __fsub_rn(p.y, ky[t]);
                        float d2 = __fadd_rn(__fmul_rn(dx, dx), __fmul_rn(dy, dy));
                        if (d2 < 25.0f) { keep[jslot] = 0; break; }
                    }
                }
            }
        }
        __syncthreads();
    }

    // ---- phase 5: write NMS column (per sorted slot, as in reference) ----
    for (int r = 0; r < PER; ++r) {
        int s = tid + r * THREADS;
        out[s*5 + 3 + cls] = keep[s] ? ssc[s] : 0.0f;
    }
}

extern "C" void kernel_launch(void* const* d_in, const int* in_sizes, int n_in,
                              void* d_out, int out_size, void* d_ws, size_t ws_size,
                              hipStream_t stream) {
    const float* logits = (const float*)d_in[0];  // [1,4096,3]
    const float* boxes  = (const float*)d_in[1];  // [1,4096,2]
    // d_in[2] = pred_gids, unused by the reference
    const float* tsz    = (const float*)d_in[3];  // [1,2]
    float* out = (float*)d_out;                   // [1,4096,5]
    hipLaunchKernelGGL(nms_all, dim3(2), dim3(THREADS), 0, stream,
                       logits, boxes, tsz, out);
}

// Round 2
// 318.071 us; speedup vs baseline: 4.2308x; 4.2308x over previous
//
#include <hip/hip_runtime.h>
#include <stdint.h>

#define N 4096
#define PBUF 2048
#define ECAP 8192

// monotonic float32 -> uint32 mapping (order-preserving)
__device__ __forceinline__ uint32_t f2s(float f) {
    uint32_t u = __float_as_uint(f);
    return (u & 0x80000000u) ? ~u : (u | 0x80000000u);
}

// ---- K1: per-point softmax, direct outputs, pts, sort keys, scores ----
__global__ void __launch_bounds__(256)
k_prep(const float* __restrict__ logits, const float* __restrict__ boxes,
       const float* __restrict__ tsz, float* __restrict__ out,
       float2* __restrict__ pts, uint64_t* __restrict__ keys,
       float* __restrict__ scores, uint32_t* __restrict__ counter)
{
    int i = blockIdx.x * 256 + threadIdx.x;
    if (i == 0) *counter = 0;          // ws is re-poisoned each call
    if (i >= N) return;
    float w = tsz[0], h = tsz[1];
    float x0 = logits[i*3+0], x1 = logits[i*3+1], x2 = logits[i*3+2];
    float mx = fmaxf(x0, fmaxf(x1, x2));
    float e0 = expf(x0 - mx), e1 = expf(x1 - mx), e2 = expf(x2 - mx);
    float sum = e0 + e1 + e2;
    float px = boxes[i*2+0] * w, py = boxes[i*2+1] * h;
    out[i*5+0] = 1.0f - e2 / sum;      // tgt score
    out[i*5+1] = px;                   // x (exact)
    out[i*5+2] = py;                   // y (exact)
    pts[i] = make_float2(px, py);
    float s0 = e0 / sum, s1 = e1 / sum;
    scores[i]     = s0;
    scores[N + i] = s1;
    uint32_t k0 = (s0 >= 0.05f) ? f2s(s0) : 0u;   // invalid sorts last
    uint32_t k1 = (s1 >= 0.05f) ? f2s(s1) : 0u;
    // tie-break: smaller original index first under DESCENDING sort (stable)
    keys[i]     = ((uint64_t)k0 << 32) | (uint32_t)(~(uint32_t)i);
    keys[N + i] = ((uint64_t)k1 << 32) | (uint32_t)(~(uint32_t)i);
}

// ---- K2: rank-by-count (descending slot = #keys strictly greater) ----
// 256 blocks x 64 threads: blockIdx>>7 = class, &127 = 32-point segment;
// 2 threads per point, each half of j-range, combine via shfl.
__global__ void __launch_bounds__(64)
k_rank(const uint64_t* __restrict__ keys, uint32_t* __restrict__ ranks)
{
    __shared__ uint64_t sk[N];
    int tid = threadIdx.x;
    int cls = blockIdx.x >> 7, seg = blockIdx.x & 127;
    const uint64_t* kc = keys + cls * N;
    for (int r = 0; r < N / 64; ++r) sk[r*64 + tid] = kc[r*64 + tid];
    __syncthreads();
    int pt = seg * 32 + (tid & 31);
    int half = tid >> 5;               // 0 or 1
    uint64_t my = sk[pt];
    int rank = 0;
    for (int j = half * (N/2); j < (half + 1) * (N/2); ++j)
        rank += (sk[j] > my) ? 1 : 0;
    rank += __shfl_xor(rank, 32);
    if (half == 0) ranks[cls*N + pt] = (uint32_t)rank;
}

// ---- K3: all-pairs within DIST_THRESH -> global pair list ----
// balanced circular enumeration: each i checks j=(i+t)%N, t=1..N/2
__global__ void __launch_bounds__(64)
k_pairs(const float2* __restrict__ pts, uint32_t* __restrict__ pairs,
        uint32_t* __restrict__ counter, int pair_cap)
{
    __shared__ float2 sp[N];
    __shared__ uint32_t sbuf[PBUF];
    __shared__ int scount, sbase;
    int tid = threadIdx.x;
    if (tid == 0) scount = 0;
    for (int r = 0; r < N / 64; ++r) sp[r*64 + tid] = pts[r*64 + tid];
    __syncthreads();
    int i = blockIdx.x * 64 + tid;
    float2 p = sp[i];
    for (int t = 1; t <= N/2; ++t) {
        if (t == N/2 && i >= N/2) break;   // dedupe antipodal pair
        int j = (i + t) & (N - 1);
        float2 q = sp[j];
        float dx = __fsub_rn(p.x, q.x);
        float dy = __fsub_rn(p.y, q.y);
        float d2 = __fadd_rn(__fmul_rn(dx, dx), __fmul_rn(dy, dy));
        if (d2 < 25.0f) {
            int pos = atomicAdd(&scount, 1);
            if (pos < PBUF) sbuf[pos] = ((uint32_t)i << 12) | (uint32_t)j;
        }
    }
    __syncthreads();
    int cnt = min(scount, PBUF);
    if (tid == 0) sbase = (int)atomicAdd(counter, (uint32_t)cnt);
    __syncthreads();
    int base = sbase;
    for (int k = tid; k < cnt; k += 64)
        if (base + k < pair_cap) pairs[base + k] = sbuf[k];
}

// ---- K4: Jacobi fixpoint of keep[v] = valid[v] & !any(kept suppressor) ----
// Unique fixpoint on the rank-DAG == greedy NMS result. One block per class.
__global__ void __launch_bounds__(1024)
k_resolve(const uint32_t* __restrict__ pairs, const uint32_t* __restrict__ counter,
          const uint32_t* __restrict__ ranks, const float* __restrict__ scores,
          float* __restrict__ out, int pair_cap)
{
    __shared__ uint16_t r16[N];
    __shared__ float    ssc[N];
    __shared__ uint32_t validw[N/32], keepw[N/32], suppw[N/32];
    __shared__ uint32_t edges[ECAP];
    __shared__ int ecnt, schanged;
    int cls = blockIdx.x, tid = threadIdx.x;

    for (int k = tid; k < N; k += 1024) {
        r16[k] = (uint16_t)ranks[cls*N + k];
        ssc[k] = scores[cls*N + k];
    }
    if (tid == 0) ecnt = 0;
    __syncthreads();
    if (tid < N/32) {
        uint32_t wbits = 0;
        for (int b = 0; b < 32; ++b)
            if (ssc[tid*32 + b] >= 0.05f) wbits |= 1u << b;
        validw[tid] = wbits; keepw[tid] = wbits;
    }
    int pcnt = min((int)*counter, pair_cap);
    __syncthreads();

    // build directed edge list (u suppresses v if kept); drop invalid endpoints
    for (int k = tid; k < pcnt; k += 1024) {
        uint32_t pr = pairs[k];
        int a = pr >> 12, b = pr & (N - 1);
        if (ssc[a] >= 0.05f && ssc[b] >= 0.05f) {
            int u = (r16[a] < r16[b]) ? a : b;
            int v = a + b - u;
            int pos = atomicAdd(&ecnt, 1);
            if (pos < ECAP) edges[pos] = ((uint32_t)u << 12) | (uint32_t)v;
        }
    }
    __syncthreads();
    int ec = min(ecnt, ECAP);

    for (int round = 0; round < N; ++round) {
        if (tid < N/32) suppw[tid] = 0;
        if (tid == 0) schanged = 0;
        __syncthreads();
        for (int k = tid; k < ec; k += 1024) {
            uint32_t e = edges[k];
            int u = e >> 12, v = e & (N - 1);
            if ((keepw[u >> 5] >> (u & 31)) & 1u)
                atomicOr(&suppw[v >> 5], 1u << (v & 31));
        }
        __syncthreads();
        if (tid < N/32) {
            uint32_t nw = validw[tid] & ~suppw[tid];
            if (nw != keepw[tid]) { keepw[tid] = nw; schanged = 1; }
        }
        __syncthreads();
        if (!schanged) break;
    }

    // output per SORTED slot, as in reference
    for (int k = tid; k < N; k += 1024) {
        int slot = r16[k];
        bool kp = (keepw[k >> 5] >> (k & 31)) & 1u;
        out[slot*5 + 3 + cls] = kp ? ssc[k] : 0.0f;
    }
}

extern "C" void kernel_launch(void* const* d_in, const int* in_sizes, int n_in,
                              void* d_out, int out_size, void* d_ws, size_t ws_size,
                              hipStream_t stream) {
    const float* logits = (const float*)d_in[0];  // [1,4096,3]
    const float* boxes  = (const float*)d_in[1];  // [1,4096,2]
    // d_in[2] = pred_gids, unused by the reference
    const float* tsz    = (const float*)d_in[3];  // [1,2]
    float* out = (float*)d_out;                   // [1,4096,5]

    uint8_t* ws = (uint8_t*)d_ws;
    uint32_t* counter = (uint32_t*)ws;                      // @0
    float2*   pts     = (float2*)  (ws + 256);              // 32 KB
    uint64_t* keys    = (uint64_t*)(ws + 256 + 32768);      // 64 KB (2 classes)
    uint32_t* ranks   = (uint32_t*)(ws + 98560);            // 32 KB
    float*    scores  = (float*)   (ws + 131328);           // 32 KB
    uint32_t* pairs   = (uint32_t*)(ws + 164096);
    size_t pc = (ws_size > 164096) ? (ws_size - 164096) / 4 : 0;
    int pair_cap = (int)(pc < 32768 ? pc : 32768);

    hipLaunchKernelGGL(k_prep,    dim3(16),  dim3(256),  0, stream,
                       logits, boxes, tsz, out, pts, keys, scores, counter);
    hipLaunchKernelGGL(k_rank,    dim3(256), dim3(64),   0, stream, keys, ranks);
    hipLaunchKernelGGL(k_pairs,   dim3(64),  dim3(64),   0, stream,
                       pts, pairs, counter, pair_cap);
    hipLaunchKernelGGL(k_resolve, dim3(2),   dim3(1024), 0, stream,
                       pairs, counter, ranks, scores, out, pair_cap);
}

// Round 3
// 118.280 us; speedup vs baseline: 11.3770x; 2.6891x over previous
//
#include <hip/hip_runtime.h>
#include <stdint.h>

#define N 4096
#define GRID_DIM 64              // 64x64 cells of 8 px over 512x512
#define NCELLS (GRID_DIM * GRID_DIM)
#define CAP 16                   // bucket capacity (Poisson(1): overflow ~1e-15)
#define PAIR_CAP 16384
#define ECAP 8192

// monotonic float32 -> uint32 mapping (order-preserving)
__device__ __forceinline__ uint32_t f2s(float f) {
    uint32_t u = __float_as_uint(f);
    return (u & 0x80000000u) ? ~u : (u | 0x80000000u);
}

// ---- K1: softmax, direct outputs, pts, sort keys, scores, grid binning ----
__global__ void __launch_bounds__(256)
k_prep(const float* __restrict__ logits, const float* __restrict__ boxes,
       const float* __restrict__ tsz, float* __restrict__ out,
       float2* __restrict__ pts, uint64_t* __restrict__ keys,
       float* __restrict__ scores, uint32_t* __restrict__ cellcnt,
       uint16_t* __restrict__ buckets)
{
    int i = blockIdx.x * 256 + threadIdx.x;
    if (i >= N) return;
    float w = tsz[0], h = tsz[1];
    float x0 = logits[i*3+0], x1 = logits[i*3+1], x2 = logits[i*3+2];
    float mx = fmaxf(x0, fmaxf(x1, x2));
    float e0 = expf(x0 - mx), e1 = expf(x1 - mx), e2 = expf(x2 - mx);
    float sum = e0 + e1 + e2;
    float px = boxes[i*2+0] * w, py = boxes[i*2+1] * h;
    out[i*5+0] = 1.0f - e2 / sum;      // tgt score
    out[i*5+1] = px;                   // x (exact)
    out[i*5+2] = py;                   // y (exact)
    pts[i] = make_float2(px, py);
    float s0 = e0 / sum, s1 = e1 / sum;
    scores[i]     = s0;
    scores[N + i] = s1;
    uint32_t k0 = (s0 >= 0.05f) ? f2s(s0) : 0u;   // invalid sorts last
    uint32_t k1 = (s1 >= 0.05f) ? f2s(s1) : 0u;
    // tie-break: smaller original index first under DESCENDING sort (stable)
    keys[i]     = ((uint64_t)k0 << 32) | (uint32_t)(~(uint32_t)i);
    keys[N + i] = ((uint64_t)k1 << 32) | (uint32_t)(~(uint32_t)i);
    // spatial bin (8 px cells); clamp for safety
    int cx = min(max((int)(px * 0.125f), 0), GRID_DIM - 1);
    int cy = min(max((int)(py * 0.125f), 0), GRID_DIM - 1);
    int c = cy * GRID_DIM + cx;
    uint32_t pos = atomicAdd(&cellcnt[c], 1u);
    if (pos < CAP) buckets[c*CAP + pos] = (uint16_t)i;
}

// ---- K2: rank-by-count (descending slot = #keys strictly greater) ----
// 256 blocks x 256 threads: 32 points/block, 8 threads/point x 512 cmps.
__global__ void __launch_bounds__(256)
k_rank(const uint64_t* __restrict__ keys, uint32_t* __restrict__ ranks)
{
    __shared__ uint64_t sk[N];
    __shared__ uint32_t part[32][8];
    int tid = threadIdx.x;
    int cls = blockIdx.x >> 7;         // 0 or 1
    int seg = blockIdx.x & 127;        // 32-point segment
    const uint64_t* kc = keys + cls * N;
    for (int r = tid; r < N; r += 256) sk[r] = kc[r];
    __syncthreads();
    int pl  = tid & 31;                // point-local
    int sub = tid >> 5;                // 0..7
    uint64_t my = sk[seg*32 + pl];
    int cnt = 0;
    int j0 = sub * (N/8);
    #pragma unroll 4
    for (int j = j0; j < j0 + N/8; ++j) cnt += (sk[j] > my) ? 1 : 0;
    part[pl][sub] = (uint32_t)cnt;
    __syncthreads();
    if (tid < 32) {
        uint32_t r = 0;
        #pragma unroll
        for (int s = 0; s < 8; ++s) r += part[tid][s];
        ranks[cls*N + seg*32 + tid] = r;
    }
}

// ---- K3: neighbor pairs within DIST_THRESH via 3x3 cell walk ----
__global__ void __launch_bounds__(256)
k_pairs(const float2* __restrict__ pts, const uint32_t* __restrict__ cellcnt,
        const uint16_t* __restrict__ buckets, uint32_t* __restrict__ pairs,
        uint32_t* __restrict__ counter)
{
    int i = blockIdx.x * 256 + threadIdx.x;
    if (i >= N) return;
    float2 p = pts[i];
    int cx = min(max((int)(p.x * 0.125f), 0), GRID_DIM - 1);
    int cy = min(max((int)(p.y * 0.125f), 0), GRID_DIM - 1);
    for (int dy = -1; dy <= 1; ++dy) {
        int yy = cy + dy; if (yy < 0 || yy >= GRID_DIM) continue;
        for (int dx = -1; dx <= 1; ++dx) {
            int xx = cx + dx; if (xx < 0 || xx >= GRID_DIM) continue;
            int c = yy * GRID_DIM + xx;
            int n = min((int)cellcnt[c], CAP);
            for (int k = 0; k < n; ++k) {
                int j = buckets[c*CAP + k];
                if (j <= i) continue;                    // dedupe
                float2 q = pts[j];
                float ddx = __fsub_rn(p.x, q.x);
                float ddy = __fsub_rn(p.y, q.y);
                float d2 = __fadd_rn(__fmul_rn(ddx, ddx), __fmul_rn(ddy, ddy));
                if (d2 < 25.0f) {
                    uint32_t pos = atomicAdd(counter, 1u);
                    if (pos < PAIR_CAP)
                        pairs[pos] = ((uint32_t)i << 12) | (uint32_t)j;
                }
            }
        }
    }
}

// ---- K4: Jacobi fixpoint of keep[v] = valid[v] & !any(kept suppressor) ----
// Unique fixpoint on the rank-DAG == greedy NMS result. One block per class.
__global__ void __launch_bounds__(1024)
k_resolve(const uint32_t* __restrict__ pairs, const uint32_t* __restrict__ counter,
          const uint32_t* __restrict__ ranks, const float* __restrict__ scores,
          float* __restrict__ out)
{
    __shared__ uint16_t r16[N];
    __shared__ float    ssc[N];
    __shared__ uint32_t validw[N/32], keepw[N/32], suppw[N/32];
    __shared__ uint32_t edges[ECAP];
    __shared__ int ecnt, schanged;
    int cls = blockIdx.x, tid = threadIdx.x;

    for (int k = tid; k < N; k += 1024) {
        r16[k] = (uint16_t)ranks[cls*N + k];
        ssc[k] = scores[cls*N + k];
    }
    if (tid == 0) ecnt = 0;
    __syncthreads();
    if (tid < N/32) {
        uint32_t wbits = 0;
        for (int b = 0; b < 32; ++b)
            if (ssc[tid*32 + b] >= 0.05f) wbits |= 1u << b;
        validw[tid] = wbits; keepw[tid] = wbits;
    }
    int pcnt = min((int)*counter, PAIR_CAP);
    __syncthreads();

    // directed edges u->v (rank u < rank v); drop invalid endpoints
    for (int k = tid; k < pcnt; k += 1024) {
        uint32_t pr = pairs[k];
        int a = pr >> 12, b = pr & (N - 1);
        if (ssc[a] >= 0.05f && ssc[b] >= 0.05f) {
            int u = (r16[a] < r16[b]) ? a : b;
            int v = a + b - u;
            int pos = atomicAdd(&ecnt, 1);
            if (pos < ECAP) edges[pos] = ((uint32_t)u << 12) | (uint32_t)v;
        }
    }
    __syncthreads();
    int ec = min(ecnt, ECAP);

    for (int round = 0; round < N; ++round) {
        if (tid < N/32) suppw[tid] = 0;
        if (tid == 0) schanged = 0;
        __syncthreads();
        for (int k = tid; k < ec; k += 1024) {
            uint32_t e = edges[k];
            int u = e >> 12, v = e & (N - 1);
            if ((keepw[u >> 5] >> (u & 31)) & 1u)
                atomicOr(&suppw[v >> 5], 1u << (v & 31));
        }
        __syncthreads();
        if (tid < N/32) {
            uint32_t nw = validw[tid] & ~suppw[tid];
            if (nw != keepw[tid]) { keepw[tid] = nw; schanged = 1; }
        }
        __syncthreads();
        if (!schanged) break;
    }

    // output per SORTED slot, as in reference
    for (int k = tid; k < N; k += 1024) {
        int slot = r16[k];
        bool kp = (keepw[k >> 5] >> (k & 31)) & 1u;
        out[slot*5 + 3 + cls] = kp ? ssc[k] : 0.0f;
    }
}

extern "C" void kernel_launch(void* const* d_in, const int* in_sizes, int n_in,
                              void* d_out, int out_size, void* d_ws, size_t ws_size,
                              hipStream_t stream) {
    const float* logits = (const float*)d_in[0];  // [1,4096,3]
    const float* boxes  = (const float*)d_in[1];  // [1,4096,2]
    // d_in[2] = pred_gids, unused by the reference
    const float* tsz    = (const float*)d_in[3];  // [1,2]
    float* out = (float*)d_out;                   // [1,4096,5]

    uint8_t* ws = (uint8_t*)d_ws;
    uint32_t* counter = (uint32_t*)ws;                        // @0       (4 B)
    uint32_t* cellcnt = (uint32_t*)(ws + 256);                // 16 KB
    uint16_t* buckets = (uint16_t*)(ws + 16640);              // 128 KB
    float2*   pts     = (float2*)  (ws + 147712);             // 32 KB
    uint64_t* keys    = (uint64_t*)(ws + 180480);             // 64 KB (2 cls)
    uint32_t* ranks   = (uint32_t*)(ws + 246016);             // 32 KB
    float*    scores  = (float*)   (ws + 278784);             // 32 KB
    uint32_t* pairs   = (uint32_t*)(ws + 311552);             // 64 KB

    // zero counter + cell counts (ws is re-poisoned to 0xAA before each call)
    hipMemsetAsync(ws, 0, 16640, stream);

    hipLaunchKernelGGL(k_prep,    dim3(16),  dim3(256),  0, stream,
                       logits, boxes, tsz, out, pts, keys, scores, cellcnt, buckets);
    hipLaunchKernelGGL(k_rank,    dim3(256), dim3(256),  0, stream, keys, ranks);
    hipLaunchKernelGGL(k_pairs,   dim3(16),  dim3(256),  0, stream,
                       pts, cellcnt, buckets, pairs, counter);
    hipLaunchKernelGGL(k_resolve, dim3(2),   dim3(1024), 0, stream,
                       pairs, counter, ranks, scores, out);
}